// Round 6
// baseline (301.148 us; speedup 1.0000x reference)
//
#include <hip/hip_runtime.h>
#include <hip/hip_bf16.h>
#include <cstdint>
#include <cstddef>

typedef __bf16 bf16;
typedef __attribute__((ext_vector_type(8))) __bf16 bf16x8;
typedef __attribute__((ext_vector_type(4))) float f32x4;
typedef __attribute__((ext_vector_type(16))) float f32x16;
typedef __attribute__((ext_vector_type(4))) float floatx4;
typedef __attribute__((ext_vector_type(4))) unsigned short ushort4_t;

// Problem constants
#define NTOK 8192
#define DIMM 1152
#define NH   16
#define HD   72
#define SEGS 4
#define SEGL 2048

__device__ __forceinline__ void gload16(const void* gsrc, void* ldst) {
  __builtin_amdgcn_global_load_lds(
      (const __attribute__((address_space(1))) void*)gsrc,
      (__attribute__((address_space(3))) void*)ldst,
      16, 0, 0);
}

__device__ __forceinline__ unsigned pk2(float a, float b) {
  unsigned short x = __builtin_bit_cast(unsigned short, (bf16)a);
  unsigned short y = __builtin_bit_cast(unsigned short, (bf16)b);
  return (unsigned)x | ((unsigned)y << 16);
}

// ---------------- f32 -> bf16 elementwise convert (8 elems/thread) -------------
__global__ __launch_bounds__(256) void k_cvt(const float* __restrict__ src,
                                             bf16* __restrict__ dst, int n8) {
  int i = blockIdx.x * 256 + threadIdx.x;
  if (i >= n8) return;
  const floatx4* s = (const floatx4*)src + (size_t)i * 2;
  floatx4 a = s[0], b = s[1];
  bf16x8 o;
  o[0] = (bf16)a.x; o[1] = (bf16)a.y; o[2] = (bf16)a.z; o[3] = (bf16)a.w;
  o[4] = (bf16)b.x; o[5] = (bf16)b.y; o[6] = (bf16)b.z; o[7] = (bf16)b.w;
  *((bf16x8*)dst + i) = o;
}

// ------- transpose + convert: src[R][C] f32 -> dst[Cpad][R] bf16 (pad -> 0) ----
__global__ __launch_bounds__(256) void k_twt(const float* __restrict__ src,
                                             bf16* __restrict__ dst, int R, int C) {
  __shared__ bf16 tile[64][73];
  int bc = blockIdx.x * 64, br = blockIdx.y * 64;
  int t = threadIdx.x;
#pragma unroll
  for (int i = 0; i < 16; i++) {
    int idx = i * 256 + t;
    int r = idx >> 6, c = idx & 63;
    float v = (bc + c < C) ? src[(size_t)(br + r) * C + bc + c] : 0.f;
    tile[c][r] = (bf16)v;
  }
  __syncthreads();
#pragma unroll
  for (int i = 0; i < 16; i++) {
    int idx = i * 256 + t;
    int r = idx >> 6, c = idx & 63;
    dst[(size_t)(bc + r) * R + br + c] = tile[r][c];
  }
}

// ---- pipelined bf16 GEMM: 2-slot LDS ring over 32-wide K-steps ----------------
// counted vmcnt (=NLD, the per-thread loads per step), raw barriers, lgkm drain
// before slot reuse. Per-wave tile MI*16 x NI*16. XOR-swizzled LDS (T2) via
// pre-swizzled global source. XCD-chunked blockIdx swizzle (T1).
template <int BM, int BN, int MI, int NI, int THREADS, bool OUT_F32>
__global__ __launch_bounds__(THREADS, 2) void k_gemmP(const bf16* __restrict__ A,
                                                      const bf16* __restrict__ Bt,
                                                      const float* __restrict__ bias,
                                                      void* __restrict__ Cout,
                                                      int M, int Nreal, int K, int gx) {
  __shared__ bf16 sA[2][BM * 32];
  __shared__ bf16 sB[2][BN * 32];
  constexpr int WN = BN / (NI * 16);
  constexpr int nA = (BM * 4) / THREADS;
  constexpr int nB = (BN * 4) / THREADS;
  constexpr int NLD = nA + nB;
  static_assert(NLD == 3 || NLD == 4, "vmcnt literal");
  const int t = threadIdx.x, wave = t >> 6, lane = t & 63;
  const int lr = lane & 15, lg = lane >> 4;
  const int nwg = gridDim.x, bid = blockIdx.x;
  const int swz = (bid & 7) * (nwg >> 3) + (bid >> 3);
  const int bx = swz % gx, by = swz / gx;
  const int m0 = by * BM, n0 = bx * BN;
  const int wr = wave / WN, wc = wave % WN;
  const int NS = K >> 5;

  f32x4 acc[MI][NI];
#pragma unroll
  for (int i = 0; i < MI; i++)
#pragma unroll
    for (int j = 0; j < NI; j++)
#pragma unroll
      for (int q = 0; q < 4; q++) acc[i][j][q] = 0.f;

  const bf16* Ab = A + (size_t)m0 * K;
  const bf16* Bb = Bt + (size_t)n0 * K;
  const int glsw = ((t & 3) ^ ((t >> 3) & 3)) * 8;   // pre-swizzled src group
  const int rbase = t >> 2;

  auto STAGE = [&](int slot, int k0) {
#pragma unroll
    for (int p = 0; p < nA; ++p)
      gload16(Ab + (size_t)(rbase + p * (THREADS / 4)) * K + k0 + glsw,
              (char*)&sA[slot][0] + p * (THREADS * 16) + wave * 1024);
#pragma unroll
    for (int p = 0; p < nB; ++p)
      gload16(Bb + (size_t)(rbase + p * (THREADS / 4)) * K + k0 + glsw,
              (char*)&sB[slot][0] + p * (THREADS * 16) + wave * 1024);
  };

  const int swz4 = (lr >> 1) & 3;
  const int aoff = (wr * MI * 16 + lr) * 32 + ((lg ^ swz4) * 8);
  const int boff = (wc * NI * 16 + lr) * 32 + ((lg ^ swz4) * 8);

  STAGE(0, 0);
  STAGE(1, 32);

  for (int j = 0; j < NS; ++j) {
    const int slot = j & 1;
    if (j == NS - 1) {
      asm volatile("s_waitcnt vmcnt(0)" ::: "memory");
    } else if constexpr (NLD == 3) {
      asm volatile("s_waitcnt vmcnt(3)" ::: "memory");
    } else {
      asm volatile("s_waitcnt vmcnt(4)" ::: "memory");
    }
    __builtin_amdgcn_s_barrier();         // slot j fully staged (all waves)
    __builtin_amdgcn_sched_barrier(0);
    bf16x8 av[MI], bv[NI];
#pragma unroll
    for (int mi = 0; mi < MI; mi++)
      av[mi] = *(const bf16x8*)&sA[slot][aoff + mi * 512];
#pragma unroll
    for (int ni = 0; ni < NI; ni++)
      bv[ni] = *(const bf16x8*)&sB[slot][boff + ni * 512];
    asm volatile("s_waitcnt lgkmcnt(0)" ::: "memory");
    __builtin_amdgcn_sched_barrier(0);
    __builtin_amdgcn_s_barrier();         // all waves' reads done -> slot reusable
    if (j + 2 < NS) STAGE(slot, (j + 2) * 32);
    __builtin_amdgcn_s_setprio(1);
#pragma unroll
    for (int mi = 0; mi < MI; mi++)
#pragma unroll
      for (int ni = 0; ni < NI; ni++)
        acc[mi][ni] = __builtin_amdgcn_mfma_f32_16x16x32_bf16(av[mi], bv[ni], acc[mi][ni], 0, 0, 0);
    __builtin_amdgcn_s_setprio(0);
  }

#pragma unroll
  for (int mi = 0; mi < MI; ++mi)
#pragma unroll
    for (int ni = 0; ni < NI; ++ni) {
      int col = n0 + wc * NI * 16 + ni * 16 + lr;
      if (col < Nreal) {
        float bc_ = bias[col];
#pragma unroll
        for (int j = 0; j < 4; j++) {
          int row = m0 + wr * MI * 16 + mi * 16 + lg * 4 + j;
          float v = acc[mi][ni][j] + bc_;
          if (OUT_F32)
            ((float*)Cout)[(size_t)row * Nreal + col] = v;
          else
            ((bf16*)Cout)[(size_t)row * Nreal + col] = (bf16)v;
        }
      }
    }
}

// ---------------- RoPE + repack Q,K: qkv[n][3456] -> Qp/Kp[s][h][3][2048][32] --
// Q is pre-scaled by log2(e)/sqrt(72) so attention works in exp2 domain.
__global__ __launch_bounds__(256) void k_rope(const bf16* __restrict__ qkv,
                                              const float* __restrict__ cs,
                                              const float* __restrict__ sn,
                                              bf16* __restrict__ Qp,
                                              bf16* __restrict__ Kp) {
  int n = blockIdx.x;
  int s = n >> 11, l = n & 2047;
  const bf16* row = qkv + (size_t)n * (3 * DIMM);
  const float* cr = cs + (size_t)n * HD;
  const float* sr = sn + (size_t)n * HD;
  const float QS = 0.17002323f;  // log2(e)/sqrt(72)
  for (int e = threadIdx.x; e < 3072; e += 256) {
    int which = e / 1536;             // 0=q, 1=k
    int r = e - which * 1536;
    int h = r / 96;
    int d = r - h * 96;
    float v = 0.f;
    if (d < HD) {
      int base = which * DIMM + h * HD;
      float x = (float)row[base + d];
      float o = (d < 36) ? -(float)row[base + d + 36] : (float)row[base + d - 36];
      v = x * cr[d] + o * sr[d];
      if (which == 0) v *= QS;
    }
    bf16* dst = which ? Kp : Qp;
    dst[(((size_t)(s * NH + h) * 3 + (d >> 5)) * SEGL + l) * 32 + (d & 31)] = (bf16)v;
  }
}

// ---------------- V repack (transpose): qkv v-part -> Vt[s][h][96][2048] -------
// Row HD (=72) is 1.0: PV MFMA accumulates the softmax denominator for free.
__global__ __launch_bounds__(256) void k_vrep(const bf16* __restrict__ qkv,
                                              bf16* __restrict__ Vt) {
  int s = blockIdx.z, h = blockIdx.y, l0 = blockIdx.x * 64;
  __shared__ bf16 tl[64][73];
  int t = threadIdx.x;
  for (int idx = t; idx < 64 * HD; idx += 256) {
    int l = idx / HD, d = idx - l * HD;
    tl[l][d] = qkv[(size_t)(s * SEGL + l0 + l) * (3 * DIMM) + 2 * DIMM + h * HD + d];
  }
  __syncthreads();
  for (int idx = t; idx < 96 * 64; idx += 256) {
    int d = idx >> 6, l = idx & 63;
    bf16 v = (d < HD) ? tl[l][d] : ((d == HD) ? (bf16)1.f : (bf16)0.f);
    Vt[((size_t)(s * NH + h) * 96 + d) * SEGL + l0 + l] = v;
  }
}

// ---------------- flash attention, software-pipelined across tiles -------------
// Iteration t: pack/PV(t) -> barrier -> stage(t+2) -> QK^T(t+1).
// P-pack VALU of one wave overlaps MFMA clusters of others (setprio);
// staging is 2 tiles ahead (a full iteration of latency cover).
__global__ __launch_bounds__(256, 2) void k_attn(const bf16* __restrict__ Qg,
                                                 const bf16* __restrict__ Kg,
                                                 const bf16* __restrict__ Vg,
                                                 bf16* __restrict__ Oo) {
  __shared__ bf16 sK[2][3 * 64 * 32];   // 2 x 12 KB
  __shared__ bf16 sV[2][96 * 64];       // 2 x 12 KB
  const int t = threadIdx.x, wave = t >> 6, lane = t & 63;
  const int c = lane & 31, hi = lane >> 5;
  const int s = blockIdx.z, h = blockIdx.y, q0 = blockIdx.x * 256;
  const bf16* Qb = Qg + (size_t)(s * NH + h) * 3 * SEGL * 32;
  const bf16* Kb = Kg + (size_t)(s * NH + h) * 3 * SEGL * 32;
  const bf16* Vb = Vg + (size_t)(s * NH + h) * 96 * SEGL;

  auto STAGEKV = [&](int kv0, int b) {
#pragma unroll
    for (int i = 0; i < 3; i++) {
      int ch = wave * 3 + i;
      int kk = ch >> 2;
      int r = (ch & 3) * 16 + (lane >> 2);
      int g = (lane & 3) ^ ((r >> 1) & 3);
      gload16(Kb + (size_t)kk * (SEGL * 32) + (size_t)(kv0 + r) * 32 + g * 8,
              (char*)sK[b] + ch * 1024);
    }
#pragma unroll
    for (int i = 0; i < 3; i++) {
      int ch = wave * 3 + i;
      int r = ch * 8 + (lane >> 3);
      int g = (lane & 7) ^ (r & 7);
      gload16(Vb + (size_t)r * SEGL + kv0 + g * 8, (char*)sV[b] + ch * 1024);
    }
  };

  // ---- Q fragments: direct global -> registers (constant across kv tiles) ----
  bf16x8 Qf[2][5];
#pragma unroll
  for (int sni = 0; sni < 2; sni++)
#pragma unroll
    for (int kk = 0; kk < 5; kk++) {
      int qr = q0 + wave * 64 + sni * 32 + c;
      Qf[sni][kk] = *(const bf16x8*)&Qb[(size_t)(kk >> 1) * (SEGL * 32) +
                                        (size_t)qr * 32 + ((kk & 1) * 2 + hi) * 8];
    }

  f32x16 accO[3][2];
#pragma unroll
  for (int df = 0; df < 3; df++)
#pragma unroll
    for (int sni = 0; sni < 2; sni++)
#pragma unroll
      for (int r = 0; r < 16; r++) accO[df][sni][r] = 0.f;

  f32x16 S[2][2];

  auto QKT = [&](int b) {
#pragma unroll
    for (int smi = 0; smi < 2; smi++)
#pragma unroll
      for (int sni = 0; sni < 2; sni++)
#pragma unroll
        for (int r = 0; r < 16; r++) S[smi][sni][r] = 0.f;
    __builtin_amdgcn_s_setprio(1);
#pragma unroll
    for (int kk = 0; kk < 5; kk++) {
      bf16x8 Kf[2];
#pragma unroll
      for (int smi = 0; smi < 2; smi++) {
        int kr = smi * 32 + c;
        int g = (((kk & 1) * 2 + hi) ^ ((kr >> 1) & 3));
        Kf[smi] = *(const bf16x8*)&sK[b][(kk >> 1) * 2048 + kr * 32 + g * 8];
      }
#pragma unroll
      for (int smi = 0; smi < 2; smi++)
#pragma unroll
        for (int sni = 0; sni < 2; sni++)
          S[smi][sni] = __builtin_amdgcn_mfma_f32_32x32x16_bf16(Kf[smi], Qf[sni][kk], S[smi][sni], 0, 0, 0);
    }
    __builtin_amdgcn_s_setprio(0);
  };

  STAGEKV(0, 0);
  STAGEKV(64, 1);
  __syncthreads();
  QKT(0);

  for (int tile = 0; tile < 32; ++tile) {
    const int buf = tile & 1;
    // ===== softmax pack + PV, in two smi-halves (register pressure) =====
#pragma unroll
    for (int half = 0; half < 2; ++half) {
      unsigned pbu[2][2][4];
#pragma unroll
      for (int k2 = 0; k2 < 2; ++k2)
#pragma unroll
        for (int sni = 0; sni < 2; sni++) {
          const int base = k2 * 8;
          unsigned u0 = pk2(__builtin_amdgcn_exp2f(S[half][sni][base + 0]),
                            __builtin_amdgcn_exp2f(S[half][sni][base + 1]));
          unsigned u1 = pk2(__builtin_amdgcn_exp2f(S[half][sni][base + 2]),
                            __builtin_amdgcn_exp2f(S[half][sni][base + 3]));
          unsigned u2 = pk2(__builtin_amdgcn_exp2f(S[half][sni][base + 4]),
                            __builtin_amdgcn_exp2f(S[half][sni][base + 5]));
          unsigned u3 = pk2(__builtin_amdgcn_exp2f(S[half][sni][base + 6]),
                            __builtin_amdgcn_exp2f(S[half][sni][base + 7]));
          asm volatile("v_permlane32_swap_b32 %0, %1" : "+v"(u0), "+v"(u2));
          asm volatile("v_permlane32_swap_b32 %0, %1" : "+v"(u1), "+v"(u3));
          pbu[k2][sni][0] = u0; pbu[k2][sni][1] = u1;
          pbu[k2][sni][2] = u2; pbu[k2][sni][3] = u3;
        }
      __builtin_amdgcn_s_setprio(1);
#pragma unroll
      for (int k2 = 0; k2 < 2; ++k2) {
        const int kk = half * 2 + k2;
        bf16x8 Vf[3];
#pragma unroll
        for (int df = 0; df < 3; df++) {
          int dr = df * 32 + c;
          int g = ((kk * 2 + hi) ^ (dr & 7));
          Vf[df] = *(const bf16x8*)&sV[buf][dr * 64 + g * 8];
        }
#pragma unroll
        for (int sni = 0; sni < 2; sni++) {
          union { bf16x8 v; unsigned u[4]; } pb;
          pb.u[0] = pbu[k2][sni][0]; pb.u[1] = pbu[k2][sni][1];
          pb.u[2] = pbu[k2][sni][2]; pb.u[3] = pbu[k2][sni][3];
#pragma unroll
          for (int df = 0; df < 3; df++)
            accO[df][sni] = __builtin_amdgcn_mfma_f32_32x32x16_bf16(Vf[df], pb.v, accO[df][sni], 0, 0, 0);
        }
      }
      __builtin_amdgcn_s_setprio(0);
    }

    if (tile + 1 < 32) {
      __syncthreads();                       // tile t+1 staged; tile t readers done
      if (tile + 2 < 32) STAGEKV((tile + 2) * 64, buf);
      QKT(buf ^ 1);
    }
  }

  // ===== write O (token-major), 8 B packed stores =====
#pragma unroll
  for (int sni = 0; sni < 2; sni++) {
    float lown = accO[2][sni][4];
    float lv = lown + __shfl_xor(lown, 32, 64);
    float inv = 1.f / lv;
    int token = s * SEGL + q0 + wave * 64 + sni * 32 + c;
#pragma unroll
    for (int df = 0; df < 3; df++)
#pragma unroll
      for (int rg = 0; rg < 4; rg++) {
        int d0 = df * 32 + rg * 8 + hi * 4;
        if (d0 < HD) {
          ushort4_t w;
          w[0] = __builtin_bit_cast(unsigned short, (bf16)(accO[df][sni][rg * 4 + 0] * inv));
          w[1] = __builtin_bit_cast(unsigned short, (bf16)(accO[df][sni][rg * 4 + 1] * inv));
          w[2] = __builtin_bit_cast(unsigned short, (bf16)(accO[df][sni][rg * 4 + 2] * inv));
          w[3] = __builtin_bit_cast(unsigned short, (bf16)(accO[df][sni][rg * 4 + 3] * inv));
          *(ushort4_t*)&Oo[(size_t)token * DIMM + h * HD + d0] = w;
        }
      }
  }
}

// -------------------------------------------------------------------------------
extern "C" void kernel_launch(void* const* d_in, const int* in_sizes, int n_in,
                              void* d_out, int out_size, void* d_ws, size_t ws_size,
                              hipStream_t stream) {
  (void)in_sizes; (void)n_in; (void)out_size; (void)ws_size;
  const float* hs     = (const float*)d_in[0];
  const float* cosp   = (const float*)d_in[1];
  const float* sinp   = (const float*)d_in[2];
  const float* w_qkv  = (const float*)d_in[4];
  const float* b_qkv  = (const float*)d_in[5];
  const float* w_proj = (const float*)d_in[6];
  const float* b_proj = (const float*)d_in[7];
  float* out = (float*)d_out;

  char* ws = (char*)d_ws;
  bf16* hsb    = (bf16*)(ws + 0);          // 18874368
  bf16* wprojT = (bf16*)(ws + 26836992);   //  2654208
  bf16* qkv    = (bf16*)(ws + 29491200);   // 56623104
  bf16* Qp     = (bf16*)(ws + 86114304);   // 25165824
  bf16* Kp     = (bf16*)(ws + 111280128);  // 25165824
  bf16* Vt     = (bf16*)(ws + 136445952);  // 25165824
  bf16* ao     = (bf16*)(ws + 161611776);  // 18874368
  // wqkvT (padded to 3584 rows) aliases ao: its lifetime ends before attn.
  bf16* wqkvT  = (bf16*)(ws + 161611776);

  k_cvt<<<4608, 256, 0, stream>>>(hs, hsb, 1179648);
  k_twt<<<dim3(56, 18), 256, 0, stream>>>(w_qkv, wqkvT, 1152, 3456);   // 3584-pad
  k_twt<<<dim3(18, 18), 256, 0, stream>>>(w_proj, wprojT, 1152, 1152);
  k_gemmP<128, 256, 4, 4, 512, false><<<896, 512, 0, stream>>>(
      hsb, wqkvT, b_qkv, (void*)qkv, 8192, 3456, 1152, 14);
  k_rope<<<8192, 256, 0, stream>>>(qkv, cosp, sinp, Qp, Kp);
  k_vrep<<<dim3(32, 16, 4), 256, 0, stream>>>(qkv, Vt);
  k_attn<<<dim3(8, 16, 4), 256, 0, stream>>>(Qp, Kp, Vt, ao);
  k_gemmP<128, 128, 4, 4, 256, true><<<576, 256, 0, stream>>>(
      ao, wprojT, b_proj, (void*)out, 8192, 1152, 1152, 9);
}

// Round 7
// 293.913 us; speedup vs baseline: 1.0246x; 1.0246x over previous
//
#include <hip/hip_runtime.h>
#include <hip/hip_bf16.h>
#include <cstdint>
#include <cstddef>

typedef __bf16 bf16;
typedef __attribute__((ext_vector_type(8))) __bf16 bf16x8;
typedef __attribute__((ext_vector_type(4))) float f32x4;
typedef __attribute__((ext_vector_type(16))) float f32x16;
typedef __attribute__((ext_vector_type(4))) float floatx4;
typedef __attribute__((ext_vector_type(4))) unsigned short ushort4_t;

// Problem constants
#define NTOK 8192
#define DIMM 1152
#define NH   16
#define HD   72
#define SEGS 4
#define SEGL 2048

__device__ __forceinline__ void gload16(const void* gsrc, void* ldst) {
  __builtin_amdgcn_global_load_lds(
      (const __attribute__((address_space(1))) void*)gsrc,
      (__attribute__((address_space(3))) void*)ldst,
      16, 0, 0);
}

__device__ __forceinline__ unsigned pk2(float a, float b) {
  unsigned short x = __builtin_bit_cast(unsigned short, (bf16)a);
  unsigned short y = __builtin_bit_cast(unsigned short, (bf16)b);
  return (unsigned)x | ((unsigned)y << 16);
}

// ---------------- f32 -> bf16 elementwise convert (8 elems/thread) -------------
__global__ __launch_bounds__(256) void k_cvt(const float* __restrict__ src,
                                             bf16* __restrict__ dst, int n8) {
  int i = blockIdx.x * 256 + threadIdx.x;
  if (i >= n8) return;
  const floatx4* s = (const floatx4*)src + (size_t)i * 2;
  floatx4 a = s[0], b = s[1];
  bf16x8 o;
  o[0] = (bf16)a.x; o[1] = (bf16)a.y; o[2] = (bf16)a.z; o[3] = (bf16)a.w;
  o[4] = (bf16)b.x; o[5] = (bf16)b.y; o[6] = (bf16)b.z; o[7] = (bf16)b.w;
  *((bf16x8*)dst + i) = o;
}

// ------- transpose + convert: src[R][C] f32 -> dst[Cpad][R] bf16 (pad -> 0) ----
__global__ __launch_bounds__(256) void k_twt(const float* __restrict__ src,
                                             bf16* __restrict__ dst, int R, int C) {
  __shared__ bf16 tile[64][73];
  int bc = blockIdx.x * 64, br = blockIdx.y * 64;
  int t = threadIdx.x;
#pragma unroll
  for (int i = 0; i < 16; i++) {
    int idx = i * 256 + t;
    int r = idx >> 6, c = idx & 63;
    float v = (bc + c < C) ? src[(size_t)(br + r) * C + bc + c] : 0.f;
    tile[c][r] = (bf16)v;
  }
  __syncthreads();
#pragma unroll
  for (int i = 0; i < 16; i++) {
    int idx = i * 256 + t;
    int r = idx >> 6, c = idx & 63;
    dst[(size_t)(bc + r) * R + br + c] = tile[r][c];
  }
}

// ---- pipelined bf16 GEMM: 3-slot LDS ring over 32-wide K-steps, ONE barrier ---
// per step. vmcnt counted (=NLD, never 0 until last). Slot safety: stage(j+2)
// writes slot (j+2)%3; the laggiest wave past barrier(j) reads slot j%3, and
// its step-(j-1) reads were lgkm-drained before it reached barrier(j).
template <int BM, int BN, int MI, int NI, int THREADS, bool OUT_F32>
__global__ __launch_bounds__(THREADS, 2) void k_gemmP(const bf16* __restrict__ A,
                                                      const bf16* __restrict__ Bt,
                                                      const float* __restrict__ bias,
                                                      void* __restrict__ Cout,
                                                      int M, int Nreal, int K, int gx) {
  __shared__ bf16 sA[3][BM * 32];
  __shared__ bf16 sB[3][BN * 32];
  constexpr int WN = BN / (NI * 16);
  constexpr int nA = (BM * 4) / THREADS;
  constexpr int nB = (BN * 4) / THREADS;
  constexpr int NLD = nA + nB;
  static_assert(NLD == 3 || NLD == 4, "vmcnt literal");
  const int t = threadIdx.x, wave = t >> 6, lane = t & 63;
  const int lr = lane & 15, lg = lane >> 4;
  const int nwg = gridDim.x, bid = blockIdx.x;
  const int swz = (bid & 7) * (nwg >> 3) + (bid >> 3);
  const int bx = swz % gx, by = swz / gx;
  const int m0 = by * BM, n0 = bx * BN;
  const int wr = wave / WN, wc = wave % WN;
  const int NS = K >> 5;

  f32x4 acc[MI][NI];
#pragma unroll
  for (int i = 0; i < MI; i++)
#pragma unroll
    for (int j = 0; j < NI; j++)
#pragma unroll
      for (int q = 0; q < 4; q++) acc[i][j][q] = 0.f;

  const bf16* Ab = A + (size_t)m0 * K;
  const bf16* Bb = Bt + (size_t)n0 * K;
  const int glsw = ((t & 3) ^ ((t >> 3) & 3)) * 8;   // pre-swizzled src group
  const int rbase = t >> 2;

  auto STAGE = [&](int slot, int k0) {
#pragma unroll
    for (int p = 0; p < nA; ++p)
      gload16(Ab + (size_t)(rbase + p * (THREADS / 4)) * K + k0 + glsw,
              (char*)&sA[slot][0] + p * (THREADS * 16) + wave * 1024);
#pragma unroll
    for (int p = 0; p < nB; ++p)
      gload16(Bb + (size_t)(rbase + p * (THREADS / 4)) * K + k0 + glsw,
              (char*)&sB[slot][0] + p * (THREADS * 16) + wave * 1024);
  };

  const int swz4 = (lr >> 1) & 3;
  const int aoff = (wr * MI * 16 + lr) * 32 + ((lg ^ swz4) * 8);
  const int boff = (wc * NI * 16 + lr) * 32 + ((lg ^ swz4) * 8);

  STAGE(0, 0);
  STAGE(1, 32);

  int slot = 0;
  for (int j = 0; j < NS; ++j) {
    if (j == NS - 1) {
      asm volatile("s_waitcnt vmcnt(0)" ::: "memory");
    } else if constexpr (NLD == 3) {
      asm volatile("s_waitcnt vmcnt(3)" ::: "memory");
    } else {
      asm volatile("s_waitcnt vmcnt(4)" ::: "memory");
    }
    __builtin_amdgcn_s_barrier();         // slot j fully staged (all waves)
    __builtin_amdgcn_sched_barrier(0);
    bf16x8 av[MI], bv[NI];
#pragma unroll
    for (int mi = 0; mi < MI; mi++)
      av[mi] = *(const bf16x8*)&sA[slot][aoff + mi * 512];
#pragma unroll
    for (int ni = 0; ni < NI; ni++)
      bv[ni] = *(const bf16x8*)&sB[slot][boff + ni * 512];
    asm volatile("s_waitcnt lgkmcnt(0)" ::: "memory");
    __builtin_amdgcn_sched_barrier(0);
    if (j + 2 < NS) {
      int s2 = slot + 2; if (s2 >= 3) s2 -= 3;
      STAGE(s2, (j + 2) * 32);
    }
    __builtin_amdgcn_s_setprio(1);
#pragma unroll
    for (int mi = 0; mi < MI; mi++)
#pragma unroll
      for (int ni = 0; ni < NI; ni++)
        acc[mi][ni] = __builtin_amdgcn_mfma_f32_16x16x32_bf16(av[mi], bv[ni], acc[mi][ni], 0, 0, 0);
    __builtin_amdgcn_s_setprio(0);
    if (++slot == 3) slot = 0;
  }

#pragma unroll
  for (int mi = 0; mi < MI; ++mi)
#pragma unroll
    for (int ni = 0; ni < NI; ++ni) {
      int col = n0 + wc * NI * 16 + ni * 16 + lr;
      if (col < Nreal) {
        float bc_ = bias[col];
#pragma unroll
        for (int j = 0; j < 4; j++) {
          int row = m0 + wr * MI * 16 + mi * 16 + lg * 4 + j;
          float v = acc[mi][ni][j] + bc_;
          if (OUT_F32)
            ((float*)Cout)[(size_t)row * Nreal + col] = v;
          else
            ((bf16*)Cout)[(size_t)row * Nreal + col] = (bf16)v;
        }
      }
    }
}

// ---------------- RoPE + repack Q,K: qkv[n][3456] -> Qp/Kp[s][h][3][2048][32] --
// Q is pre-scaled by log2(e)/sqrt(72) so attention works in exp2 domain.
__global__ __launch_bounds__(256) void k_rope(const bf16* __restrict__ qkv,
                                              const float* __restrict__ cs,
                                              const float* __restrict__ sn,
                                              bf16* __restrict__ Qp,
                                              bf16* __restrict__ Kp) {
  int n = blockIdx.x;
  int s = n >> 11, l = n & 2047;
  const bf16* row = qkv + (size_t)n * (3 * DIMM);
  const float* cr = cs + (size_t)n * HD;
  const float* sr = sn + (size_t)n * HD;
  const float QS = 0.17002323f;  // log2(e)/sqrt(72)
  for (int e = threadIdx.x; e < 3072; e += 256) {
    int which = e / 1536;             // 0=q, 1=k
    int r = e - which * 1536;
    int h = r / 96;
    int d = r - h * 96;
    float v = 0.f;
    if (d < HD) {
      int base = which * DIMM + h * HD;
      float x = (float)row[base + d];
      float o = (d < 36) ? -(float)row[base + d + 36] : (float)row[base + d - 36];
      v = x * cr[d] + o * sr[d];
      if (which == 0) v *= QS;
    }
    bf16* dst = which ? Kp : Qp;
    dst[(((size_t)(s * NH + h) * 3 + (d >> 5)) * SEGL + l) * 32 + (d & 31)] = (bf16)v;
  }
}

// ---------------- V repack (transpose): qkv v-part -> Vt[s][h][96][2048] -------
// Row HD (=72) is 1.0: PV MFMA accumulates the softmax denominator for free.
__global__ __launch_bounds__(256) void k_vrep(const bf16* __restrict__ qkv,
                                              bf16* __restrict__ Vt) {
  int s = blockIdx.z, h = blockIdx.y, l0 = blockIdx.x * 64;
  __shared__ bf16 tl[64][73];
  int t = threadIdx.x;
  for (int idx = t; idx < 64 * HD; idx += 256) {
    int l = idx / HD, d = idx - l * HD;
    tl[l][d] = qkv[(size_t)(s * SEGL + l0 + l) * (3 * DIMM) + 2 * DIMM + h * HD + d];
  }
  __syncthreads();
  for (int idx = t; idx < 96 * 64; idx += 256) {
    int d = idx >> 6, l = idx & 63;
    bf16 v = (d < HD) ? tl[l][d] : ((d == HD) ? (bf16)1.f : (bf16)0.f);
    Vt[((size_t)(s * NH + h) * 96 + d) * SEGL + l0 + l] = v;
  }
}

// ---------------- flash attention (round-5 structure + XCD grouping) -----------
// 1-D grid of 512; bid decode co-locates all 8 q-tiles of one (s,h) K/V panel
// on ONE XCD (dispatch round-robins XCDs by linear id): panel is L2-resident
// instead of being HBM-fetched by 8 XCDs.
__global__ __launch_bounds__(256, 2) void k_attn(const bf16* __restrict__ Qg,
                                                 const bf16* __restrict__ Kg,
                                                 const bf16* __restrict__ Vg,
                                                 bf16* __restrict__ Oo) {
  __shared__ bf16 sK[2][3 * 64 * 32];   // 2 x 12 KB
  __shared__ bf16 sV[2][96 * 64];       // 2 x 12 KB
  const int t = threadIdx.x, wave = t >> 6, lane = t & 63;
  const int c = lane & 31, hi = lane >> 5;
  const int bid = blockIdx.x;
  const int g = ((bid >> 6) << 3) | (bid & 7);   // group 0..63 (xcd = g%8)
  const int qt = (bid >> 3) & 7;
  const int s = g >> 4, h = g & 15, q0 = qt * 256;
  const bf16* Qb = Qg + (size_t)(s * NH + h) * 3 * SEGL * 32;
  const bf16* Kb = Kg + (size_t)(s * NH + h) * 3 * SEGL * 32;
  const bf16* Vb = Vg + (size_t)(s * NH + h) * 96 * SEGL;

  // ---- Q fragments: direct global -> registers (constant across kv tiles) ----
  bf16x8 Qf[2][5];
#pragma unroll
  for (int sni = 0; sni < 2; sni++)
#pragma unroll
    for (int kk = 0; kk < 5; kk++) {
      int qr = q0 + wave * 64 + sni * 32 + c;
      Qf[sni][kk] = *(const bf16x8*)&Qb[(size_t)(kk >> 1) * (SEGL * 32) +
                                        (size_t)qr * 32 + ((kk & 1) * 2 + hi) * 8];
    }

  // ---- stage K,V tile 0 into buffer 0 ----
#pragma unroll
  for (int i = 0; i < 3; i++) {
    int ch = wave * 3 + i;
    int kk = ch >> 2;
    int r = (ch & 3) * 16 + (lane >> 2);
    int gg = (lane & 3) ^ ((r >> 1) & 3);
    gload16(Kb + (size_t)kk * (SEGL * 32) + (size_t)r * 32 + gg * 8,
            (char*)sK[0] + ch * 1024);
  }
#pragma unroll
  for (int i = 0; i < 3; i++) {
    int ch = wave * 3 + i;
    int r = ch * 8 + (lane >> 3);
    int gg = (lane & 7) ^ (r & 7);
    gload16(Vb + (size_t)r * SEGL + gg * 8, (char*)sV[0] + ch * 1024);
  }
  __syncthreads();

  f32x16 accO[3][2];
#pragma unroll
  for (int df = 0; df < 3; df++)
#pragma unroll
    for (int sni = 0; sni < 2; sni++)
#pragma unroll
      for (int r = 0; r < 16; r++) accO[df][sni][r] = 0.f;
  f32x16 ZC;
#pragma unroll
  for (int r = 0; r < 16; r++) ZC[r] = 0.f;

  int cur = 0;
  for (int tile = 0; tile < 32; ++tile) {
    // ---- issue next-tile staging into the other buffer (overlaps compute) ----
    if (tile + 1 < 32) {
      int kv0 = (tile + 1) * 64;
#pragma unroll
      for (int i = 0; i < 3; i++) {
        int ch = wave * 3 + i;
        int kk = ch >> 2;
        int r = (ch & 3) * 16 + (lane >> 2);
        int gg = (lane & 3) ^ ((r >> 1) & 3);
        gload16(Kb + (size_t)kk * (SEGL * 32) + (size_t)(kv0 + r) * 32 + gg * 8,
                (char*)sK[cur ^ 1] + ch * 1024);
      }
#pragma unroll
      for (int i = 0; i < 3; i++) {
        int ch = wave * 3 + i;
        int r = ch * 8 + (lane >> 3);
        int gg = (lane & 7) ^ (r & 7);
        gload16(Vb + (size_t)r * SEGL + kv0 + gg * 8, (char*)sV[cur ^ 1] + ch * 1024);
      }
    }

    // ===== S^T = K · Q  (kk=0 uses the persistent zero C-operand) =====
    f32x16 S[2][2];
    __builtin_amdgcn_s_setprio(1);
#pragma unroll
    for (int kk = 0; kk < 5; kk++) {
      bf16x8 Kf[2];
#pragma unroll
      for (int smi = 0; smi < 2; smi++) {
        int kr = smi * 32 + c;
        int gg = (((kk & 1) * 2 + hi) ^ ((kr >> 1) & 3));
        Kf[smi] = *(const bf16x8*)&sK[cur][(kk >> 1) * 2048 + kr * 32 + gg * 8];
      }
#pragma unroll
      for (int smi = 0; smi < 2; smi++)
#pragma unroll
        for (int sni = 0; sni < 2; sni++)
          S[smi][sni] = __builtin_amdgcn_mfma_f32_32x32x16_bf16(
              Kf[smi], Qf[sni][kk], kk ? S[smi][sni] : ZC, 0, 0, 0);
    }
    __builtin_amdgcn_s_setprio(0);

    // ===== O^T += V^T · P^T  (P = exp2(S) folded into the pack; no max) =====
    __builtin_amdgcn_s_setprio(1);
#pragma unroll
    for (int kk = 0; kk < 4; kk++) {
      bf16x8 Vf[3];
#pragma unroll
      for (int df = 0; df < 3; df++) {
        int dr = df * 32 + c;
        int gg = ((kk * 2 + hi) ^ (dr & 7));
        Vf[df] = *(const bf16x8*)&sV[cur][dr * 64 + gg * 8];
      }
#pragma unroll
      for (int sni = 0; sni < 2; sni++) {
        const int smi = kk >> 1;
        const int base = (kk & 1) * 8;
        unsigned u0 = pk2(__builtin_amdgcn_exp2f(S[smi][sni][base + 0]),
                          __builtin_amdgcn_exp2f(S[smi][sni][base + 1]));
        unsigned u1 = pk2(__builtin_amdgcn_exp2f(S[smi][sni][base + 2]),
                          __builtin_amdgcn_exp2f(S[smi][sni][base + 3]));
        unsigned u2 = pk2(__builtin_amdgcn_exp2f(S[smi][sni][base + 4]),
                          __builtin_amdgcn_exp2f(S[smi][sni][base + 5]));
        unsigned u3 = pk2(__builtin_amdgcn_exp2f(S[smi][sni][base + 6]),
                          __builtin_amdgcn_exp2f(S[smi][sni][base + 7]));
        asm volatile("v_permlane32_swap_b32 %0, %1" : "+v"(u0), "+v"(u2));
        asm volatile("v_permlane32_swap_b32 %0, %1" : "+v"(u1), "+v"(u3));
        union { bf16x8 v; unsigned u[4]; } pb;
        pb.u[0] = u0; pb.u[1] = u1; pb.u[2] = u2; pb.u[3] = u3;
#pragma unroll
        for (int df = 0; df < 3; df++)
          accO[df][sni] = __builtin_amdgcn_mfma_f32_32x32x16_bf16(Vf[df], pb.v, accO[df][sni], 0, 0, 0);
      }
    }
    __builtin_amdgcn_s_setprio(0);

    __syncthreads();
    cur ^= 1;
  }

  // ===== write O (token-major), 8 B packed stores =====
#pragma unroll
  for (int sni = 0; sni < 2; sni++) {
    float lown = accO[2][sni][4];
    float lv = lown + __shfl_xor(lown, 32, 64);
    float inv = 1.f / lv;
    int token = s * SEGL + q0 + wave * 64 + sni * 32 + c;
#pragma unroll
    for (int df = 0; df < 3; df++)
#pragma unroll
      for (int rg = 0; rg < 4; rg++) {
        int d0 = df * 32 + rg * 8 + hi * 4;
        if (d0 < HD) {
          ushort4_t w;
          w[0] = __builtin_bit_cast(unsigned short, (bf16)(accO[df][sni][rg * 4 + 0] * inv));
          w[1] = __builtin_bit_cast(unsigned short, (bf16)(accO[df][sni][rg * 4 + 1] * inv));
          w[2] = __builtin_bit_cast(unsigned short, (bf16)(accO[df][sni][rg * 4 + 2] * inv));
          w[3] = __builtin_bit_cast(unsigned short, (bf16)(accO[df][sni][rg * 4 + 3] * inv));
          *(ushort4_t*)&Oo[(size_t)token * DIMM + h * HD + d0] = w;
        }
      }
  }
}

// -------------------------------------------------------------------------------
extern "C" void kernel_launch(void* const* d_in, const int* in_sizes, int n_in,
                              void* d_out, int out_size, void* d_ws, size_t ws_size,
                              hipStream_t stream) {
  (void)in_sizes; (void)n_in; (void)out_size; (void)ws_size;
  const float* hs     = (const float*)d_in[0];
  const float* cosp   = (const float*)d_in[1];
  const float* sinp   = (const float*)d_in[2];
  const float* w_qkv  = (const float*)d_in[4];
  const float* b_qkv  = (const float*)d_in[5];
  const float* w_proj = (const float*)d_in[6];
  const float* b_proj = (const float*)d_in[7];
  float* out = (float*)d_out;

  char* ws = (char*)d_ws;
  bf16* hsb    = (bf16*)(ws + 0);          // 18874368
  bf16* wprojT = (bf16*)(ws + 26836992);   //  2654208
  bf16* qkv    = (bf16*)(ws + 29491200);   // 56623104
  bf16* Qp     = (bf16*)(ws + 86114304);   // 25165824
  bf16* Kp     = (bf16*)(ws + 111280128);  // 25165824
  bf16* Vt     = (bf16*)(ws + 136445952);  // 25165824
  bf16* ao     = (bf16*)(ws + 161611776);  // 18874368
  // wqkvT (padded to 3584 rows) aliases ao: its lifetime ends before attn.
  bf16* wqkvT  = (bf16*)(ws + 161611776);

  k_cvt<<<4608, 256, 0, stream>>>(hs, hsb, 1179648);
  k_twt<<<dim3(56, 18), 256, 0, stream>>>(w_qkv, wqkvT, 1152, 3456);   // 3584-pad
  k_twt<<<dim3(18, 18), 256, 0, stream>>>(w_proj, wprojT, 1152, 1152);
  k_gemmP<128, 256, 4, 4, 512, false><<<896, 512, 0, stream>>>(
      hsb, wqkvT, b_qkv, (void*)qkv, 8192, 3456, 1152, 14);
  k_rope<<<8192, 256, 0, stream>>>(qkv, cosp, sinp, Qp, Kp);
  k_vrep<<<dim3(32, 16, 4), 256, 0, stream>>>(qkv, Vt);
  k_attn<<<512, 256, 0, stream>>>(Qp, Kp, Vt, ao);
  k_gemmP<128, 128, 4, 4, 256, true><<<576, 256, 0, stream>>>(
      ao, wprojT, b_proj, (void*)out, 8192, 1152, 1152, 9);
}

// Round 8
// 289.805 us; speedup vs baseline: 1.0391x; 1.0142x over previous
//
#include <hip/hip_runtime.h>
#include <hip/hip_bf16.h>
#include <cstdint>
#include <cstddef>

typedef __bf16 bf16;
typedef __attribute__((ext_vector_type(8))) __bf16 bf16x8;
typedef __attribute__((ext_vector_type(4))) float f32x4;
typedef __attribute__((ext_vector_type(16))) float f32x16;
typedef __attribute__((ext_vector_type(4))) float floatx4;
typedef __attribute__((ext_vector_type(4))) unsigned short ushort4_t;
typedef __attribute__((ext_vector_type(2))) unsigned uint2_t;
typedef __attribute__((ext_vector_type(4))) unsigned uint4_t;

// Problem constants
#define NTOK 8192
#define DIMM 1152
#define NH   16
#define HD   72
#define SEGS 4
#define SEGL 2048

__device__ __forceinline__ void gload16(const void* gsrc, void* ldst) {
  __builtin_amdgcn_global_load_lds(
      (const __attribute__((address_space(1))) void*)gsrc,
      (__attribute__((address_space(3))) void*)ldst,
      16, 0, 0);
}

// single-instruction pack: low16 = bf16(a), high16 = bf16(b)
__device__ __forceinline__ unsigned cvtpk(float a, float b) {
  unsigned r;
  asm volatile("v_cvt_pk_bf16_f32 %0, %1, %2" : "=v"(r) : "v"(a), "v"(b));
  return r;
}

// ---------------- f32 -> bf16 elementwise convert (8 elems/thread) -------------
__global__ __launch_bounds__(256) void k_cvt(const float* __restrict__ src,
                                             bf16* __restrict__ dst, int n8) {
  int i = blockIdx.x * 256 + threadIdx.x;
  if (i >= n8) return;
  const floatx4* s = (const floatx4*)src + (size_t)i * 2;
  floatx4 a = s[0], b = s[1];
  uint4_t o;
  o[0] = cvtpk(a.x, a.y);
  o[1] = cvtpk(a.z, a.w);
  o[2] = cvtpk(b.x, b.y);
  o[3] = cvtpk(b.z, b.w);
  *((uint4_t*)dst + i) = o;
}

// ------- transpose + convert: src[R][C] f32 -> dst[Cpad][R] bf16 (pad -> 0) ----
__global__ __launch_bounds__(256) void k_twt(const float* __restrict__ src,
                                             bf16* __restrict__ dst, int R, int C) {
  __shared__ bf16 tile[64][73];
  int bc = blockIdx.x * 64, br = blockIdx.y * 64;
  int t = threadIdx.x;
#pragma unroll
  for (int i = 0; i < 16; i++) {
    int idx = i * 256 + t;
    int r = idx >> 6, c = idx & 63;
    float v = (bc + c < C) ? src[(size_t)(br + r) * C + bc + c] : 0.f;
    tile[c][r] = (bf16)v;
  }
  __syncthreads();
#pragma unroll
  for (int i = 0; i < 16; i++) {
    int idx = i * 256 + t;
    int r = idx >> 6, c = idx & 63;
    dst[(size_t)(bc + r) * R + br + c] = tile[r][c];
  }
}

// ---- pipelined bf16 GEMM: 3-slot LDS ring over 32-wide K-steps, ONE barrier ---
template <int BM, int BN, int MI, int NI, int THREADS, bool OUT_F32>
__global__ __launch_bounds__(THREADS, 2) void k_gemmP(const bf16* __restrict__ A,
                                                      const bf16* __restrict__ Bt,
                                                      const float* __restrict__ bias,
                                                      void* __restrict__ Cout,
                                                      int M, int Nreal, int K, int gx) {
  __shared__ bf16 sA[3][BM * 32];
  __shared__ bf16 sB[3][BN * 32];
  constexpr int WN = BN / (NI * 16);
  constexpr int nA = (BM * 4) / THREADS;
  constexpr int nB = (BN * 4) / THREADS;
  constexpr int NLD = nA + nB;
  static_assert(NLD == 3 || NLD == 4, "vmcnt literal");
  const int t = threadIdx.x, wave = t >> 6, lane = t & 63;
  const int lr = lane & 15, lg = lane >> 4;
  const int nwg = gridDim.x, bid = blockIdx.x;
  const int swz = (bid & 7) * (nwg >> 3) + (bid >> 3);
  const int bx = swz % gx, by = swz / gx;
  const int m0 = by * BM, n0 = bx * BN;
  const int wr = wave / WN, wc = wave % WN;
  const int NS = K >> 5;

  f32x4 acc[MI][NI];
#pragma unroll
  for (int i = 0; i < MI; i++)
#pragma unroll
    for (int j = 0; j < NI; j++)
#pragma unroll
      for (int q = 0; q < 4; q++) acc[i][j][q] = 0.f;

  const bf16* Ab = A + (size_t)m0 * K;
  const bf16* Bb = Bt + (size_t)n0 * K;
  const int glsw = ((t & 3) ^ ((t >> 3) & 3)) * 8;   // pre-swizzled src group
  const int rbase = t >> 2;

  auto STAGE = [&](int slot, int k0) {
#pragma unroll
    for (int p = 0; p < nA; ++p)
      gload16(Ab + (size_t)(rbase + p * (THREADS / 4)) * K + k0 + glsw,
              (char*)&sA[slot][0] + p * (THREADS * 16) + wave * 1024);
#pragma unroll
    for (int p = 0; p < nB; ++p)
      gload16(Bb + (size_t)(rbase + p * (THREADS / 4)) * K + k0 + glsw,
              (char*)&sB[slot][0] + p * (THREADS * 16) + wave * 1024);
  };

  const int swz4 = (lr >> 1) & 3;
  const int aoff = (wr * MI * 16 + lr) * 32 + ((lg ^ swz4) * 8);
  const int boff = (wc * NI * 16 + lr) * 32 + ((lg ^ swz4) * 8);

  STAGE(0, 0);
  STAGE(1, 32);

  int slot = 0;
  for (int j = 0; j < NS; ++j) {
    if (j == NS - 1) {
      asm volatile("s_waitcnt vmcnt(0)" ::: "memory");
    } else if constexpr (NLD == 3) {
      asm volatile("s_waitcnt vmcnt(3)" ::: "memory");
    } else {
      asm volatile("s_waitcnt vmcnt(4)" ::: "memory");
    }
    __builtin_amdgcn_s_barrier();
    __builtin_amdgcn_sched_barrier(0);
    bf16x8 av[MI], bv[NI];
#pragma unroll
    for (int mi = 0; mi < MI; mi++)
      av[mi] = *(const bf16x8*)&sA[slot][aoff + mi * 512];
#pragma unroll
    for (int ni = 0; ni < NI; ni++)
      bv[ni] = *(const bf16x8*)&sB[slot][boff + ni * 512];
    asm volatile("s_waitcnt lgkmcnt(0)" ::: "memory");
    __builtin_amdgcn_sched_barrier(0);
    if (j + 2 < NS) {
      int s2 = slot + 2; if (s2 >= 3) s2 -= 3;
      STAGE(s2, (j + 2) * 32);
    }
    __builtin_amdgcn_s_setprio(1);
#pragma unroll
    for (int mi = 0; mi < MI; mi++)
#pragma unroll
      for (int ni = 0; ni < NI; ni++)
        acc[mi][ni] = __builtin_amdgcn_mfma_f32_16x16x32_bf16(av[mi], bv[ni], acc[mi][ni], 0, 0, 0);
    __builtin_amdgcn_s_setprio(0);
    if (++slot == 3) slot = 0;
  }

#pragma unroll
  for (int mi = 0; mi < MI; ++mi)
#pragma unroll
    for (int ni = 0; ni < NI; ++ni) {
      int col = n0 + wc * NI * 16 + ni * 16 + lr;
      if (col < Nreal) {
        float bc_ = bias[col];
#pragma unroll
        for (int j = 0; j < 4; j++) {
          int row = m0 + wr * MI * 16 + mi * 16 + lg * 4 + j;
          float v = acc[mi][ni][j] + bc_;
          if (OUT_F32)
            ((float*)Cout)[(size_t)row * Nreal + col] = v;
          else
            ((bf16*)Cout)[(size_t)row * Nreal + col] = (bf16)v;
        }
      }
    }
}

// ---------------- RoPE + repack Q,K: qkv[n][3456] -> Qp/Kp[s][h][3][2048][32] --
__global__ __launch_bounds__(256) void k_rope(const bf16* __restrict__ qkv,
                                              const float* __restrict__ cs,
                                              const float* __restrict__ sn,
                                              bf16* __restrict__ Qp,
                                              bf16* __restrict__ Kp) {
  int n = blockIdx.x;
  int s = n >> 11, l = n & 2047;
  const bf16* row = qkv + (size_t)n * (3 * DIMM);
  const float* cr = cs + (size_t)n * HD;
  const float* sr = sn + (size_t)n * HD;
  const float QS = 0.17002323f;  // log2(e)/sqrt(72)
  for (int e = threadIdx.x; e < 3072; e += 256) {
    int which = e / 1536;             // 0=q, 1=k
    int r = e - which * 1536;
    int h = r / 96;
    int d = r - h * 96;
    float v = 0.f;
    if (d < HD) {
      int base = which * DIMM + h * HD;
      float x = (float)row[base + d];
      float o = (d < 36) ? -(float)row[base + d + 36] : (float)row[base + d - 36];
      v = x * cr[d] + o * sr[d];
      if (which == 0) v *= QS;
    }
    bf16* dst = which ? Kp : Qp;
    dst[(((size_t)(s * NH + h) * 3 + (d >> 5)) * SEGL + l) * 32 + (d & 31)] = (bf16)v;
  }
}

// ---------------- V repack (transpose): qkv v-part -> Vt[s][h][96][2048] -------
// Row HD (=72) is 1.0: PV MFMA accumulates the softmax denominator for free.
__global__ __launch_bounds__(256) void k_vrep(const bf16* __restrict__ qkv,
                                              bf16* __restrict__ Vt) {
  int s = blockIdx.z, h = blockIdx.y, l0 = blockIdx.x * 64;
  __shared__ bf16 tl[64][73];
  int t = threadIdx.x;
  for (int idx = t; idx < 64 * HD; idx += 256) {
    int l = idx / HD, d = idx - l * HD;
    tl[l][d] = qkv[(size_t)(s * SEGL + l0 + l) * (3 * DIMM) + 2 * DIMM + h * HD + d];
  }
  __syncthreads();
  for (int idx = t; idx < 96 * 64; idx += 256) {
    int d = idx >> 6, l = idx & 63;
    bf16 v = (d < HD) ? tl[l][d] : ((d == HD) ? (bf16)1.f : (bf16)0.f);
    Vt[((size_t)(s * NH + h) * 96 + d) * SEGL + l0 + l] = v;
  }
}

// ---------------- flash attention (XCD-grouped, cvt_pk pack, ptr-inc staging) --
__global__ __launch_bounds__(256, 2) void k_attn(const bf16* __restrict__ Qg,
                                                 const bf16* __restrict__ Kg,
                                                 const bf16* __restrict__ Vg,
                                                 bf16* __restrict__ Oo) {
  __shared__ bf16 sK[2][3 * 64 * 32];   // 2 x 12 KB
  __shared__ bf16 sV[2][96 * 64];       // 2 x 12 KB
  const int t = threadIdx.x, wave = t >> 6, lane = t & 63;
  const int c = lane & 31, hi = lane >> 5;
  const int bid = blockIdx.x;
  const int g = ((bid >> 6) << 3) | (bid & 7);   // group 0..63 (xcd = g%8)
  const int qt = (bid >> 3) & 7;
  const int s = g >> 4, h = g & 15, q0 = qt * 256;
  const bf16* Qb = Qg + (size_t)(s * NH + h) * 3 * SEGL * 32;
  const bf16* Kb = Kg + (size_t)(s * NH + h) * 3 * SEGL * 32;
  const bf16* Vb = Vg + (size_t)(s * NH + h) * 96 * SEGL;

  // ---- per-lane staging source pointers (advanced per tile) ----
  const bf16* kq[3];
  const bf16* vq[3];
#pragma unroll
  for (int i = 0; i < 3; i++) {
    int ch = wave * 3 + i;
    int kk = ch >> 2;
    int r = (ch & 3) * 16 + (lane >> 2);
    int gg = (lane & 3) ^ ((r >> 1) & 3);
    kq[i] = Kb + (size_t)kk * (SEGL * 32) + (size_t)r * 32 + gg * 8;
    int rv = ch * 8 + (lane >> 3);
    int gv = (lane & 7) ^ (rv & 7);
    vq[i] = Vb + (size_t)rv * SEGL + gv * 8;
  }

  // ---- Q fragments: direct global -> registers (constant across kv tiles) ----
  bf16x8 Qf[2][5];
#pragma unroll
  for (int sni = 0; sni < 2; sni++)
#pragma unroll
    for (int kk = 0; kk < 5; kk++) {
      int qr = q0 + wave * 64 + sni * 32 + c;
      Qf[sni][kk] = *(const bf16x8*)&Qb[(size_t)(kk >> 1) * (SEGL * 32) +
                                        (size_t)qr * 32 + ((kk & 1) * 2 + hi) * 8];
    }

  // ---- stage K,V tile 0 into buffer 0 ----
#pragma unroll
  for (int i = 0; i < 3; i++) {
    gload16(kq[i], (char*)sK[0] + (wave * 3 + i) * 1024);
    gload16(vq[i], (char*)sV[0] + (wave * 3 + i) * 1024);
    kq[i] += 2048;   // next 64 kv rows
    vq[i] += 64;     // next 64 kv cols
  }
  __syncthreads();

  f32x16 accO[3][2];
#pragma unroll
  for (int df = 0; df < 3; df++)
#pragma unroll
    for (int sni = 0; sni < 2; sni++)
#pragma unroll
      for (int r = 0; r < 16; r++) accO[df][sni][r] = 0.f;
  f32x16 ZC;
#pragma unroll
  for (int r = 0; r < 16; r++) ZC[r] = 0.f;

  int cur = 0;
  for (int tile = 0; tile < 32; ++tile) {
    // ---- issue next-tile staging into the other buffer (overlaps compute) ----
    if (tile + 1 < 32) {
#pragma unroll
      for (int i = 0; i < 3; i++) {
        gload16(kq[i], (char*)sK[cur ^ 1] + (wave * 3 + i) * 1024);
        gload16(vq[i], (char*)sV[cur ^ 1] + (wave * 3 + i) * 1024);
        kq[i] += 2048;
        vq[i] += 64;
      }
    }

    // ===== S^T = K · Q  (kk=0 uses the persistent zero C-operand) =====
    f32x16 S[2][2];
    __builtin_amdgcn_s_setprio(1);
#pragma unroll
    for (int kk = 0; kk < 5; kk++) {
      bf16x8 Kf[2];
#pragma unroll
      for (int smi = 0; smi < 2; smi++) {
        int kr = smi * 32 + c;
        int gg = (((kk & 1) * 2 + hi) ^ ((kr >> 1) & 3));
        Kf[smi] = *(const bf16x8*)&sK[cur][(kk >> 1) * 2048 + kr * 32 + gg * 8];
      }
#pragma unroll
      for (int smi = 0; smi < 2; smi++)
#pragma unroll
        for (int sni = 0; sni < 2; sni++)
          S[smi][sni] = __builtin_amdgcn_mfma_f32_32x32x16_bf16(
              Kf[smi], Qf[sni][kk], kk ? S[smi][sni] : ZC, 0, 0, 0);
    }
    __builtin_amdgcn_s_setprio(0);

    // ===== O^T += V^T · P^T  (P = exp2(S); cvt_pk pack; permlane exchange) =====
    __builtin_amdgcn_s_setprio(1);
#pragma unroll
    for (int kk = 0; kk < 4; kk++) {
      bf16x8 Vf[3];
#pragma unroll
      for (int df = 0; df < 3; df++) {
        int dr = df * 32 + c;
        int gg = ((kk * 2 + hi) ^ (dr & 7));
        Vf[df] = *(const bf16x8*)&sV[cur][dr * 64 + gg * 8];
      }
#pragma unroll
      for (int sni = 0; sni < 2; sni++) {
        const int smi = kk >> 1;
        const int base = (kk & 1) * 8;
        unsigned u0 = cvtpk(__builtin_amdgcn_exp2f(S[smi][sni][base + 0]),
                            __builtin_amdgcn_exp2f(S[smi][sni][base + 1]));
        unsigned u1 = cvtpk(__builtin_amdgcn_exp2f(S[smi][sni][base + 2]),
                            __builtin_amdgcn_exp2f(S[smi][sni][base + 3]));
        unsigned u2 = cvtpk(__builtin_amdgcn_exp2f(S[smi][sni][base + 4]),
                            __builtin_amdgcn_exp2f(S[smi][sni][base + 5]));
        unsigned u3 = cvtpk(__builtin_amdgcn_exp2f(S[smi][sni][base + 6]),
                            __builtin_amdgcn_exp2f(S[smi][sni][base + 7]));
        asm volatile("v_permlane32_swap_b32 %0, %1" : "+v"(u0), "+v"(u2));
        asm volatile("v_permlane32_swap_b32 %0, %1" : "+v"(u1), "+v"(u3));
        union { bf16x8 v; unsigned u[4]; } pb;
        pb.u[0] = u0; pb.u[1] = u1; pb.u[2] = u2; pb.u[3] = u3;
#pragma unroll
        for (int df = 0; df < 3; df++)
          accO[df][sni] = __builtin_amdgcn_mfma_f32_32x32x16_bf16(Vf[df], pb.v, accO[df][sni], 0, 0, 0);
      }
    }
    __builtin_amdgcn_s_setprio(0);

    __syncthreads();
    cur ^= 1;
  }

  // ===== write O (token-major), 8 B packed stores =====
#pragma unroll
  for (int sni = 0; sni < 2; sni++) {
    float lown = accO[2][sni][4];
    float lv = lown + __shfl_xor(lown, 32, 64);
    float inv = 1.f / lv;
    int token = s * SEGL + q0 + wave * 64 + sni * 32 + c;
#pragma unroll
    for (int df = 0; df < 3; df++)
#pragma unroll
      for (int rg = 0; rg < 4; rg++) {
        int d0 = df * 32 + rg * 8 + hi * 4;
        if (d0 < HD) {
          uint2_t w;
          w[0] = cvtpk(accO[df][sni][rg * 4 + 0] * inv, accO[df][sni][rg * 4 + 1] * inv);
          w[1] = cvtpk(accO[df][sni][rg * 4 + 2] * inv, accO[df][sni][rg * 4 + 3] * inv);
          *(uint2_t*)&Oo[(size_t)token * DIMM + h * HD + d0] = w;
        }
      }
  }
}

// -------------------------------------------------------------------------------
extern "C" void kernel_launch(void* const* d_in, const int* in_sizes, int n_in,
                              void* d_out, int out_size, void* d_ws, size_t ws_size,
                              hipStream_t stream) {
  (void)in_sizes; (void)n_in; (void)out_size; (void)ws_size;
  const float* hs     = (const float*)d_in[0];
  const float* cosp   = (const float*)d_in[1];
  const float* sinp   = (const float*)d_in[2];
  const float* w_qkv  = (const float*)d_in[4];
  const float* b_qkv  = (const float*)d_in[5];
  const float* w_proj = (const float*)d_in[6];
  const float* b_proj = (const float*)d_in[7];
  float* out = (float*)d_out;

  char* ws = (char*)d_ws;
  bf16* hsb    = (bf16*)(ws + 0);          // 18874368
  bf16* wprojT = (bf16*)(ws + 26836992);   //  2654208
  bf16* qkv    = (bf16*)(ws + 29491200);   // 56623104
  bf16* Qp     = (bf16*)(ws + 86114304);   // 25165824
  bf16* Kp     = (bf16*)(ws + 111280128);  // 25165824
  bf16* Vt     = (bf16*)(ws + 136445952);  // 25165824
  bf16* ao     = (bf16*)(ws + 161611776);  // 18874368
  // wqkvT (padded to 3584 rows) aliases ao: its lifetime ends before attn.
  bf16* wqkvT  = (bf16*)(ws + 161611776);

  k_cvt<<<4608, 256, 0, stream>>>(hs, hsb, 1179648);
  k_twt<<<dim3(56, 18), 256, 0, stream>>>(w_qkv, wqkvT, 1152, 3456);   // 3584-pad
  k_twt<<<dim3(18, 18), 256, 0, stream>>>(w_proj, wprojT, 1152, 1152);
  k_gemmP<128, 256, 4, 4, 512, false><<<896, 512, 0, stream>>>(
      hsb, wqkvT, b_qkv, (void*)qkv, 8192, 3456, 1152, 14);
  k_rope<<<8192, 256, 0, stream>>>(qkv, cosp, sinp, Qp, Kp);
  k_vrep<<<dim3(32, 16, 4), 256, 0, stream>>>(qkv, Vt);
  k_attn<<<512, 256, 0, stream>>>(Qp, Kp, Vt, ao);
  k_gemmP<128, 128, 4, 4, 256, true><<<576, 256, 0, stream>>>(
      ao, wprojT, b_proj, (void*)out, 8192, 1152, 1152, 9);
}